// Round 9
// baseline (10872.185 us; speedup 1.0000x reference)
//
#include <hip/hip_runtime.h>
#include <hip/hip_bf16.h>
#include <hip/hip_fp16.h>
#include <math.h>

#define HH 384
#define WW 384
#define HW (HH*WW)
#define PH 386
#define PW 386
#define BB 4
#define CC 8
#define NLAYERS 5
#define CGITERS 10
#define PI_F 3.14159265358979323846f

typedef __attribute__((ext_vector_type(8))) short short8;
typedef __attribute__((ext_vector_type(4))) float floatx4;

struct cf { float x, y; };
__device__ __forceinline__ cf cadd(cf a, cf b){ cf r; r.x=a.x+b.x; r.y=a.y+b.y; return r; }
__device__ __forceinline__ cf csub(cf a, cf b){ cf r; r.x=a.x-b.x; r.y=a.y-b.y; return r; }
__device__ __forceinline__ cf cmul(cf a, cf b){ cf r; r.x=a.x*b.x - a.y*b.y; r.y=a.x*b.y + a.y*b.x; return r; }
__device__ __forceinline__ cf csqr(cf a){ cf r; r.x = a.x*a.x - a.y*a.y; r.y = 2.f*a.x*a.y; return r; }
__device__ __forceinline__ cf shflxor(cf v, int m){ cf r; r.x = __shfl_xor(v.x, m); r.y = __shfl_xor(v.y, m); return r; }
__device__ __forceinline__ int brev7(int l){ return (int)(__brev((unsigned)l) >> 25); }
__device__ __forceinline__ int padi(int i){ return i + (i >> 3); }
__device__ __forceinline__ cf h2cf(__half2 h){ float2 f = __half22float2(h); cf r; r.x = f.x; r.y = f.y; return r; }
__device__ __forceinline__ __half2 cf2h(cf v){ return __floats2half2_rn(v.x, v.y); }

__device__ __forceinline__ void radix3(cf a0, cf a1, cf a2, float s3, cf y[3]) {
  float tx = a1.x + a2.x, ty_ = a1.y + a2.y;
  float ux = a1.x - a2.x, uy = a1.y - a2.y;
  y[0].x = a0.x + tx;              y[0].y = a0.y + ty_;
  y[1].x = a0.x - 0.5f*tx - s3*uy; y[1].y = a0.y - 0.5f*ty_ + s3*ux;
  y[2].x = a0.x - 0.5f*tx + s3*uy; y[2].y = a0.y - 0.5f*ty_ - s3*ux;
}

// 384-point DFT across one 64-lane wave. SIGN=-1 fwd, +1 inverse (no 1/N scale).
// ONE sincos; all other twiddles derived by complex mul/squaring.
template<int SIGN>
__device__ __forceinline__ void fft384_wave(int l, const cf v[6], cf uA[3], cf uB[3]) {
  const float s3 = SIGN * 0.8660254037844386f;
  radix3(v[0], v[2], v[4], s3, uA);
  radix3(v[1], v[3], v[5], s3, uB);
  float sA, cA;
  __sincosf(SIGN * (2.0f * PI_F / 384.0f) * (float)l, &sA, &cA);
  cf wA1; wA1.x = cA; wA1.y = sA;
  cf wA2 = csqr(wA1);
  cf w6; w6.x = 0.5f; w6.y = s3;            // exp(SIGN*i*pi/3)
  cf wB1 = cmul(wA1, w6);
  cf wB2 = csqr(wB1);
  uA[1] = cmul(uA[1], wA1); uA[2] = cmul(uA[2], wA2);
  uB[1] = cmul(uB[1], wB1); uB[2] = cmul(uB[2], wB2);
  cf u = cmul(wA2, wA1);                    // exp(SIGN*i*pi*l/64)
  #pragma unroll
  for (int k1 = 0; k1 < 3; ++k1) {
    cf a = uA[k1], b = uB[k1];
    uA[k1] = cadd(a, b);
    uB[k1] = cmul(csub(a, b), u);
  }
  #pragma unroll
  for (int h = 32; h >= 1; h >>= 1) {
    u = csqr(u);                             // exp(SIGN*i*pi*l/h)
    const bool up = (l & h) != 0;
    #pragma unroll
    for (int k1 = 0; k1 < 3; ++k1) {
      cf pa = shflxor(uA[k1], h);
      cf pb = shflxor(uB[k1], h);
      cf na = up ? cmul(csub(uA[k1], pa), u) : cadd(uA[k1], pa);
      cf nb = up ? cmul(csub(uB[k1], pb), u) : cadd(uB[k1], pb);
      uA[k1] = na; uB[k1] = nb;
    }
  }
}

// ---------------- conv kernels ----------------
// Activations in ZERO-BORDER-PADDED NHWC bf16: act[b][py][px][c], py,px in
// [0,386), logical pixel (y,x) at (y+1,x+1). Border stays zero all launch.

__global__ void repack_mid_k(const float* __restrict__ ws_mid, __hip_bfloat16* __restrict__ wrep) {
  const int idx = blockIdx.x * 256 + threadIdx.x;
  if (idx >= 7*9*64*64) return;
  const int ci = idx & 63, co = (idx >> 6) & 63, tap = (idx >> 12) % 9, i = idx / (9*4096);
  wrep[idx] = __float2bfloat16(ws_mid[(((size_t)i*64 + co)*64 + ci)*9 + tap]);
}

// zero the 1-px border of both padded activation buffers (ws is poisoned each call)
__global__ void zero_border_k(__hip_bfloat16* __restrict__ a0, __hip_bfloat16* __restrict__ a1) {
  const int idx = blockIdx.x * 256 + threadIdx.x;
  if (idx >= 2*4*1540*8) return;
  const int s = idx & 7;
  int e = idx >> 3;
  const int buf = e / 6160; e -= buf*6160;
  const int b = e / 1540;  const int i = e - b*1540;
  int y, x;
  if (i < 386)       { y = 0;            x = i; }
  else if (i < 772)  { y = 385;          x = i - 386; }
  else if (i < 1156) { y = i - 772 + 1;  x = 0; }
  else               { y = i - 1156 + 1; x = 385; }
  __hip_bfloat16* p = (buf ? a1 : a0) + ((size_t)(b*PH + y)*PW + x)*64 + s*8;
  *(uint4*)p = make_uint4(0u, 0u, 0u, 0u);
}

__global__ void __launch_bounds__(256) conv_in_k(const float* __restrict__ xin,
                                                 const float* __restrict__ w,
                                                 const float* __restrict__ bias,
                                                 __hip_bfloat16* __restrict__ out) {
  __shared__ float tile[2][340];
  const int tx = threadIdx.x & 31, ty = threadIdx.x >> 5;
  const int x0 = blockIdx.x * 32, y0 = blockIdx.y * 8, b = blockIdx.z;
  for (int e = threadIdx.x; e < 680; e += 256) {
    int ci = e / 340, rr = e % 340;
    int iy = y0 - 1 + rr / 34, ix = x0 - 1 + rr % 34;
    float v = 0.f;
    if (iy >= 0 && iy < HH && ix >= 0 && ix < WW)
      v = xin[(b*2 + ci)*HW + iy*WW + ix];
    tile[ci][rr] = v;
  }
  __syncthreads();
  float acc[64];
  #pragma unroll
  for (int co = 0; co < 64; ++co) acc[co] = bias[co];
  #pragma unroll
  for (int ci = 0; ci < 2; ++ci) {
    float v0 = tile[ci][ty*34+tx],     v1 = tile[ci][ty*34+tx+1],     v2 = tile[ci][ty*34+tx+2];
    float v3 = tile[ci][(ty+1)*34+tx], v4 = tile[ci][(ty+1)*34+tx+1], v5 = tile[ci][(ty+1)*34+tx+2];
    float v6 = tile[ci][(ty+2)*34+tx], v7 = tile[ci][(ty+2)*34+tx+1], v8 = tile[ci][(ty+2)*34+tx+2];
    #pragma unroll
    for (int co = 0; co < 64; ++co) {
      const float* wp = w + co*18 + ci*9;
      float a = acc[co];
      a = fmaf(v0, wp[0], a); a = fmaf(v1, wp[1], a); a = fmaf(v2, wp[2], a);
      a = fmaf(v3, wp[3], a); a = fmaf(v4, wp[4], a); a = fmaf(v5, wp[5], a);
      a = fmaf(v6, wp[6], a); a = fmaf(v7, wp[7], a); a = fmaf(v8, wp[8], a);
      acc[co] = a;
    }
  }
  const size_t obase = ((size_t)(b*PH + y0 + ty + 1)*PW + (x0 + tx + 1))*64;
  #pragma unroll
  for (int s = 0; s < 8; ++s) {
    uint4 u;
    __hip_bfloat16* hp = (__hip_bfloat16*)&u;
    #pragma unroll
    for (int j = 0; j < 8; ++j) hp[j] = __float2bfloat16(acc[s*8 + j]);
    *(uint4*)(out + obase + s*8) = u;
  }
}

// MFMA implicit-GEMM mid conv, NO A-staging: fragments read directly from the
// zero-padded global buffer (coalesced 16px x 128B; taps hit L1). No barriers
// until the small epilogue transpose. Kills the round-8 staging-barrier convoy.
__global__ void __launch_bounds__(256) conv_mid_mfma_k(
    const __hip_bfloat16* __restrict__ in,    // padded NHWC
    const __hip_bfloat16* __restrict__ wrep,  // [9][64][64] bf16
    const float* __restrict__ bias,
    __hip_bfloat16* __restrict__ out, int relu) {
  __shared__ __hip_bfloat16 otile[256*72];    // 36864 B (epilogue only)
  const int tid = threadIdx.x;
  const int l = tid & 63, wv = tid >> 6;
  const int x0 = blockIdx.x * 32, y0 = blockIdx.y * 8, b = blockIdx.z;

  const int kseg = l >> 4;
  const int lr = l & 15;

  floatx4 acc[4][4];
  #pragma unroll
  for (int mt = 0; mt < 4; ++mt)
    #pragma unroll
    for (int nt = 0; nt < 4; ++nt)
      acc[mt][nt] = (floatx4){0.f, 0.f, 0.f, 0.f};

  // B prefetch (tap 0)
  const __hip_bfloat16* wlane = wrep + lr*64 + kseg*8;
  short8 bf[4][2];
  #pragma unroll
  for (int nt = 0; nt < 4; ++nt) {
    bf[nt][0] = *(const short8*)(wlane + nt*1024);
    bf[nt][1] = *(const short8*)(wlane + nt*1024 + 32);
  }

  // A base: padded row = logical + dy, padded col = logical + dx
  const __hip_bfloat16* inb = in + ((size_t)(b*PH + y0 + 2*wv)*PW + x0)*64 + kseg*8;

  #pragma unroll 1
  for (int tap = 0; tap < 9; ++tap) {
    short8 bfn[4][2];
    if (tap < 8) {
      const __hip_bfloat16* wn = wlane + (tap + 1)*4096;
      #pragma unroll
      for (int nt = 0; nt < 4; ++nt) {
        bfn[nt][0] = *(const short8*)(wn + nt*1024);
        bfn[nt][1] = *(const short8*)(wn + nt*1024 + 32);
      }
    }
    const int dy = tap / 3, dx = tap - dy*3;
    short8 af[4][2];
    #pragma unroll
    for (int mt = 0; mt < 4; ++mt) {
      const __hip_bfloat16* ap = inb + (((mt >> 1) + dy)*PW + (mt & 1)*16 + lr + dx)*64;
      af[mt][0] = *(const short8*)(ap);
      af[mt][1] = *(const short8*)(ap + 32);
    }
    #pragma unroll
    for (int mt = 0; mt < 4; ++mt)
      #pragma unroll
      for (int nt = 0; nt < 4; ++nt) {
        acc[mt][nt] = __builtin_amdgcn_mfma_f32_16x16x32_bf16(af[mt][0], bf[nt][0], acc[mt][nt], 0, 0, 0);
        acc[mt][nt] = __builtin_amdgcn_mfma_f32_16x16x32_bf16(af[mt][1], bf[nt][1], acc[mt][nt], 0, 0, 0);
      }
    if (tap < 8) {
      #pragma unroll
      for (int nt = 0; nt < 4; ++nt) { bf[nt][0] = bfn[nt][0]; bf[nt][1] = bfn[nt][1]; }
    }
  }

  // LDS-transpose epilogue -> coalesced 16B stores (single barrier in kernel)
  #pragma unroll
  for (int mt = 0; mt < 4; ++mt) {
    const int row = 2*wv + (mt >> 1);
    #pragma unroll
    for (int nt = 0; nt < 4; ++nt) {
      const int ch = nt*16 + lr;
      const float bv = bias[ch];
      #pragma unroll
      for (int rr = 0; rr < 4; ++rr) {
        const int px = (mt & 1)*16 + kseg*4 + rr;
        float v = acc[mt][nt][rr] + bv;
        if (relu) v = fmaxf(v, 0.f);
        otile[(row*32 + px)*72 + ch] = __float2bfloat16(v);
      }
    }
  }
  __syncthreads();
  #pragma unroll
  for (int iter = 0; iter < 8; ++iter) {
    const int p = iter*32 + (tid >> 3), s = tid & 7;
    const int row = p >> 5, px = p & 31;
    uint4 v = *(const uint4*)(&otile[p*72 + s*8]);
    *(uint4*)(out + ((size_t)(b*PH + y0 + row + 1)*PW + (x0 + px + 1))*64 + s*8) = v;
  }
}

// conv_out (co=2) + CG init, LDS-staged from padded buffer (no bounds checks)
__global__ void __launch_bounds__(256) conv_out_k(const __hip_bfloat16* __restrict__ in,
                                                  const float* __restrict__ w,
                                                  const float* __restrict__ bias,
                                                  const float* __restrict__ xcur,
                                                  const float* __restrict__ under,
                                                  const float* __restrict__ lam,
                                                  cf* __restrict__ r, cf* __restrict__ p,
                                                  cf* __restrict__ xc, float* __restrict__ scL) {
  __shared__ __hip_bfloat16 atile[340*72];
  __shared__ float wl[2*64*9];
  __shared__ float wsum[4];
  const int tid = threadIdx.x;
  const int tx = tid & 31, ty = tid >> 5;
  const int x0 = blockIdx.x * 32, y0 = blockIdx.y * 8, b = blockIdx.z;

  for (int e = tid; e < 340*8; e += 256) {
    int pp = e >> 3, s = e & 7;
    uint4 v = *(const uint4*)(in + ((size_t)(b*PH + y0 + pp/34)*PW + (x0 + pp%34))*64 + s*8);
    *(uint4*)(&atile[pp*72 + s*8]) = v;
  }
  for (int e = tid; e < 2*64*9; e += 256) wl[e] = w[e];
  __syncthreads();

  float a0 = bias[0], a1 = bias[1];
  #pragma unroll 1
  for (int tap = 0; tap < 9; ++tap) {
    const int dy = tap / 3, dx = tap - dy*3;
    const __hip_bfloat16* ap = &atile[((ty + dy)*34 + tx + dx)*72];
    #pragma unroll
    for (int s = 0; s < 8; ++s) {
      short8 v8 = *(const short8*)(ap + s*8);
      const __hip_bfloat16* hv = (const __hip_bfloat16*)&v8;
      #pragma unroll
      for (int j = 0; j < 8; ++j) {
        const float f = __bfloat162float(hv[j]);
        a0 = fmaf(f, wl[(s*8 + j)*9 + tap], a0);
        a1 = fmaf(f, wl[(64 + s*8 + j)*9 + tap], a1);
      }
    }
  }
  const float lamv = lam[0];
  const int y = y0 + ty, x = x0 + tx;
  const int idx2 = y*WW + x;
  float xv0 = xcur[b*2*HW + idx2],  xv1 = xcur[b*2*HW + HW + idx2];
  float u0  = under[b*2*HW + idx2], u1  = under[b*2*HW + HW + idx2];
  float r0 = u0 + lamv * (xv0 + a0);
  float r1 = u1 + lamv * (xv1 + a1);
  const int cidx = b*HW + idx2;
  cf vv; vv.x = r0; vv.y = r1;
  r[cidx] = vv; p[cidx] = vv;
  cf zz; zz.x = 0.f; zz.y = 0.f; xc[cidx] = zz;
  float partial = r0*r0 + r1*r1;
  for (int off = 32; off; off >>= 1) partial += __shfl_down(partial, off);
  const int l = tid & 63, wvid = tid >> 6;
  if (l == 0) wsum[wvid] = partial;
  __syncthreads();
  if (tid == 0) atomicAdd(&scL[b], wsum[0]+wsum[1]+wsum[2]+wsum[3]);
}

// ---------------- CG / FFT kernels ----------------
// t stored fp16 (half2 per px): halves the dominant CG HBM traffic.
// scL: rtr[it*4+b], pAp[40+it*4+b], ApAp[80+it*4+b]; rtr_new = a^2*ApAp - rtr.

__global__ void __launch_bounds__(256) pass_a_k(const cf* __restrict__ rold, cf* __restrict__ rnew,
                                                const cf* __restrict__ pold, cf* __restrict__ pnew,
                                                cf* __restrict__ xc, const cf* __restrict__ Ap,
                                                const cf* __restrict__ csm, __half2* __restrict__ t,
                                                float* __restrict__ scL, int it) {
  __shared__ cf rowbuf[4][434];
  const int l = threadIdx.x & 63, wv = threadIdx.x >> 6;
  const int y = blockIdx.x * 4 + wv;
  const int c = blockIdx.y, b = blockIdx.z;
  const int rowoff = b*HW + y*WW;
  cf pv[6];
  if (it == 0) {
    #pragma unroll
    for (int m = 0; m < 6; ++m) pv[m] = pold[rowoff + l + 64*m];
  } else {
    const float rtrp  = scL[(it-1)*4 + b];
    const float pApp  = scL[40 + (it-1)*4 + b];
    const float ApApp = scL[80 + (it-1)*4 + b];
    const float alpha = rtrp / pApp;
    const float rtrn  = alpha*alpha*ApApp - rtrp;
    const float beta  = rtrn / rtrp;
    if (blockIdx.x == 0 && c == 0 && threadIdx.x == 0) scL[it*4 + b] = rtrn;
    #pragma unroll
    for (int m = 0; m < 6; ++m) {
      const int idx = rowoff + l + 64*m;
      cf rv = rold[idx];
      cf av = Ap[idx];
      rv.x -= alpha*av.x; rv.y -= alpha*av.y;
      cf po = pold[idx];
      pv[m].x = rv.x + beta*po.x; pv[m].y = rv.y + beta*po.y;
      if (c == 0) {
        rnew[idx] = rv;
        pnew[idx] = pv[m];
        cf xv = xc[idx]; xv.x += alpha*po.x; xv.y += alpha*po.y; xc[idx] = xv;
      }
    }
  }
  const cf* crow = csm + (b*CC + c)*HW + y*WW;
  cf v[6];
  #pragma unroll
  for (int m = 0; m < 6; ++m) v[m] = cmul(crow[l + 64*m], pv[m]);
  cf uA[3], uB[3];
  fft384_wave<-1>(l, v, uA, uB);
  const int R3 = 3 * brev7(l);
  cf* rb = rowbuf[wv];                  // wave-private
  #pragma unroll
  for (int k1 = 0; k1 < 3; ++k1) { rb[padi(k1 + R3)] = uA[k1]; rb[padi(k1 + R3 + 3)] = uB[k1]; }
  __half2* trow = t + (b*CC + c)*HW + y*WW;
  #pragma unroll
  for (int m = 0; m < 6; ++m) trow[l + 64*m] = cf2h(rb[padi(l + 64*m)]);
}

__global__ void __launch_bounds__(256) pass_b_k(__half2* __restrict__ t, const float* __restrict__ mask) {
  __shared__ cf tile[431*9];
  const int b = blockIdx.z, c = blockIdx.y, x0 = blockIdx.x * 8;
  __half2* base = t + (b*CC + c)*HW;
  for (int e = threadIdx.x; e < 3072; e += 256) {
    int y = e >> 3, xx = e & 7;
    tile[padi(y)*9 + xx] = h2cf(base[y*WW + x0 + xx]);
  }
  __syncthreads();
  const int l = threadIdx.x & 63, wv = threadIdx.x >> 6;
  const int R3 = 3 * brev7(l);
  for (int rep = 0; rep < 2; ++rep) {
    const int xx = wv*2 + rep, x = x0 + xx;
    cf v[6];
    #pragma unroll
    for (int m = 0; m < 6; ++m) v[m] = tile[padi(l + 64*m)*9 + xx];
    cf uA[3], uB[3];
    fft384_wave<-1>(l, v, uA, uB);
    const float* mrow = mask + b*HW + x;
    #pragma unroll
    for (int k1 = 0; k1 < 3; ++k1) {
      float mA = mrow[(k1 + R3)*WW], mB = mrow[(k1 + R3 + 3)*WW];
      uA[k1].x *= mA; uA[k1].y *= mA; uB[k1].x *= mB; uB[k1].y *= mB;
    }
    __syncthreads();
    #pragma unroll
    for (int k1 = 0; k1 < 3; ++k1) { tile[padi(k1 + R3)*9 + xx] = uA[k1]; tile[padi(k1 + R3 + 3)*9 + xx] = uB[k1]; }
    __syncthreads();
    #pragma unroll
    for (int m = 0; m < 6; ++m) v[m] = tile[padi(l + 64*m)*9 + xx];
    fft384_wave<1>(l, v, uA, uB);
    const float s = 1.0f / 384.0f;
    #pragma unroll
    for (int k1 = 0; k1 < 3; ++k1) {
      uA[k1].x *= s; uA[k1].y *= s; uB[k1].x *= s; uB[k1].y *= s;
      tile[padi(k1 + R3)*9 + xx] = uA[k1]; tile[padi(k1 + R3 + 3)*9 + xx] = uB[k1];
    }
    __syncthreads();
  }
  for (int e = threadIdx.x; e < 3072; e += 256) {
    int y = e >> 3, xx = e & 7;
    base[y*WW + x0 + xx] = cf2h(tile[padi(y)*9 + xx]);
  }
}

// pass_c: one y-row per block (HH x BB grid), 8 coils split 2/wave, LDS reduce.
__global__ void __launch_bounds__(256) pass_c_k(const __half2* __restrict__ t, const cf* __restrict__ csm,
                                                const cf* __restrict__ p, cf* __restrict__ Ap,
                                                const float* __restrict__ lam,
                                                float* __restrict__ scL, int it) {
  __shared__ cf rowbuf[4][434];
  __shared__ cf redbuf[3][384];
  const int l = threadIdx.x & 63, wv = threadIdx.x >> 6;
  const int y = blockIdx.x, b = blockIdx.y;
  const int R3 = 3 * brev7(l);
  cf* rb = rowbuf[wv];                  // wave-private
  cf acc[6] = {};
  #pragma unroll 1
  for (int ci = 0; ci < 2; ++ci) {
    const int c = wv*2 + ci;
    const __half2* trow = t + (b*CC + c)*HW + y*WW;
    cf v[6];
    #pragma unroll
    for (int m = 0; m < 6; ++m) v[m] = h2cf(trow[l + 64*m]);
    cf uA[3], uB[3];
    fft384_wave<1>(l, v, uA, uB);
    #pragma unroll
    for (int k1 = 0; k1 < 3; ++k1) { rb[padi(k1 + R3)] = uA[k1]; rb[padi(k1 + R3 + 3)] = uB[k1]; }
    const cf* crow = csm + (b*CC + c)*HW + y*WW;
    #pragma unroll
    for (int m = 0; m < 6; ++m) {
      cf cs = crow[l + 64*m];
      cf wz = rb[padi(l + 64*m)];
      acc[m].x += cs.x*wz.x + cs.y*wz.y;
      acc[m].y += cs.x*wz.y - cs.y*wz.x;
    }
  }
  if (wv > 0) {
    #pragma unroll
    for (int m = 0; m < 6; ++m) redbuf[wv - 1][l + 64*m] = acc[m];
  }
  __syncthreads();
  if (wv == 0) {
    #pragma unroll
    for (int m = 0; m < 6; ++m) {
      #pragma unroll
      for (int j = 0; j < 3; ++j) {
        cf o = redbuf[j][l + 64*m];
        acc[m].x += o.x; acc[m].y += o.y;
      }
    }
    const float lamv = lam[0];
    const float sc384 = 1.0f / 384.0f;
    const cf* prow = p + b*HW + y*WW;
    cf* aprow = Ap + b*HW + y*WW;
    float partial = 0.f, partial2 = 0.f;
    #pragma unroll
    for (int m = 0; m < 6; ++m) {
      cf pv = prow[l + 64*m];
      cf ap; ap.x = acc[m].x*sc384 + lamv*pv.x; ap.y = acc[m].y*sc384 + lamv*pv.y;
      aprow[l + 64*m] = ap;
      partial  += pv.x*ap.x + pv.y*ap.y;
      partial2 += ap.x*ap.x + ap.y*ap.y;
    }
    #pragma unroll
    for (int off = 32; off; off >>= 1) {
      partial  += __shfl_down(partial, off);
      partial2 += __shfl_down(partial2, off);
    }
    if (l == 0) {
      atomicAdd(&scL[40 + it*4 + b], partial);
      atomicAdd(&scL[80 + it*4 + b], partial2);
    }
  }
}

// final x = xc + alpha9 * p9, planar output
__global__ void __launch_bounds__(256) final_x_k(const cf* __restrict__ xc, const cf* __restrict__ p9,
                                                 const float* __restrict__ scL, float* __restrict__ out) {
  const int idx = blockIdx.x * 256 + threadIdx.x;
  const int b = idx / HW;
  const int rem = idx - b*HW;
  const float alpha = scL[(CGITERS-1)*4 + b] / scL[40 + (CGITERS-1)*4 + b];
  cf xv = xc[idx], pv = p9[idx];
  xv.x += alpha*pv.x; xv.y += alpha*pv.y;
  out[b*2*HW + rem] = xv.x;
  out[b*2*HW + HW + rem] = xv.y;
}

__global__ void zero_sc_k(float* sc) {
  for (int i = threadIdx.x; i < NLAYERS*128; i += 256) sc[i] = 0.f;
}

extern "C" void kernel_launch(void* const* d_in, const int* in_sizes, int n_in,
                              void* d_out, int out_size, void* d_ws, size_t ws_size,
                              hipStream_t stream) {
  (void)in_sizes; (void)n_in; (void)out_size; (void)ws_size;
  const float* under  = (const float*)d_in[0];
  const cf*    csm    = (const cf*)d_in[1];
  const float* mask   = (const float*)d_in[2];
  const float* lam    = (const float*)d_in[3];
  const float* w_in   = (const float*)d_in[4];
  const float* b_in   = (const float*)d_in[5];
  const float* ws_mid = (const float*)d_in[6];
  const float* bs_mid = (const float*)d_in[7];
  const float* w_out  = (const float*)d_in[8];
  const float* b_out  = (const float*)d_in[9];
  float* xcur = (float*)d_out;

  char* bws = (char*)d_ws;
  size_t off = 0;
  auto carve = [&](size_t bytes) { char* pp = bws + off; off += (bytes + 255) & ~(size_t)255; return (void*)pp; };
  __hip_bfloat16* actA = (__hip_bfloat16*)carve((size_t)BB*PH*PW*64*2);
  __hip_bfloat16* actB = (__hip_bfloat16*)carve((size_t)BB*PH*PW*64*2);
  __half2* t = (__half2*)carve((size_t)BB*CC*HW*4);
  cf* rbuf0 = (cf*)carve((size_t)BB*HW*8);
  cf* rbuf1 = (cf*)carve((size_t)BB*HW*8);
  cf* pbuf0 = (cf*)carve((size_t)BB*HW*8);
  cf* pbuf1 = (cf*)carve((size_t)BB*HW*8);
  cf* xc    = (cf*)carve((size_t)BB*HW*8);
  cf* Ap    = (cf*)carve((size_t)BB*HW*8);
  float* sc = (float*)carve(4096);
  __hip_bfloat16* wrep = (__hip_bfloat16*)carve((size_t)7*9*64*64*2);

  hipMemcpyAsync(xcur, under, (size_t)BB*2*HW*sizeof(float), hipMemcpyDeviceToDevice, stream);

  zero_sc_k<<<1, 256, 0, stream>>>(sc);
  zero_border_k<<<(2*4*1540*8 + 255)/256, 256, 0, stream>>>(actA, actB);
  repack_mid_k<<<(7*9*64*64 + 255)/256, 256, 0, stream>>>(ws_mid, wrep);

  dim3 cgrid(WW/32, HH/8, BB);       // conv kernels (32x8 tiles)
  dim3 agrid(HH/4, CC, BB);
  dim3 bgrid(WW/8, CC, BB);
  dim3 c2grid(HH, BB);               // pass_c: one row per block
  const int egrid = BB*HW/256;

  __hip_bfloat16* bufs[2] = { actA, actB };
  cf* rb[2] = { rbuf0, rbuf1 };
  cf* pb[2] = { pbuf0, pbuf1 };

  for (int layer = 0; layer < NLAYERS; ++layer) {
    float* scL = sc + layer*128;
    conv_in_k<<<cgrid, 256, 0, stream>>>(xcur, w_in, b_in, bufs[0]);
    for (int i = 0; i < 7; ++i) {
      conv_mid_mfma_k<<<cgrid, 256, 0, stream>>>(bufs[i & 1], wrep + (size_t)i*9*4096,
                                                 bs_mid + i*64, bufs[(i + 1) & 1], (i % 2 == 0) ? 1 : 0);
    }
    conv_out_k<<<cgrid, 256, 0, stream>>>(bufs[1], w_out, b_out, xcur, under, lam,
                                          rbuf0, pbuf0, xc, scL);
    for (int it = 0; it < CGITERS; ++it) {
      cf* rold = rb[(it + 1) & 1];
      cf* rnew = rb[it & 1];
      cf* pold = pb[(it + 1) & 1];
      cf* pnew = pb[it & 1];
      if (it == 0) { rold = rbuf0; pold = pbuf0; rnew = rbuf0; pnew = pbuf0; }
      pass_a_k<<<agrid, 256, 0, stream>>>(rold, rnew, pold, pnew, xc, Ap, csm, t, scL, it);
      pass_b_k<<<bgrid, 256, 0, stream>>>(t, mask);
      pass_c_k<<<c2grid, 256, 0, stream>>>(t, csm, pnew, Ap, lam, scL, it);
    }
    final_x_k<<<egrid, 256, 0, stream>>>(xc, pb[(CGITERS - 1) & 1], scL, xcur);
  }
}

// Round 10
// 10064.520 us; speedup vs baseline: 1.0802x; 1.0802x over previous
//
#include <hip/hip_runtime.h>
#include <hip/hip_bf16.h>
#include <hip/hip_fp16.h>
#include <math.h>

#define HH 384
#define WW 384
#define HW (HH*WW)
#define PH 386
#define PW 386
#define BB 4
#define CC 8
#define NLAYERS 5
#define CGITERS 10
#define PI_F 3.14159265358979323846f

typedef __attribute__((ext_vector_type(8))) short short8;
typedef __attribute__((ext_vector_type(4))) float floatx4;

struct cf { float x, y; };
__device__ __forceinline__ cf cadd(cf a, cf b){ cf r; r.x=a.x+b.x; r.y=a.y+b.y; return r; }
__device__ __forceinline__ cf csub(cf a, cf b){ cf r; r.x=a.x-b.x; r.y=a.y-b.y; return r; }
__device__ __forceinline__ cf cmul(cf a, cf b){ cf r; r.x=a.x*b.x - a.y*b.y; r.y=a.x*b.y + a.y*b.x; return r; }
__device__ __forceinline__ cf csqr(cf a){ cf r; r.x = a.x*a.x - a.y*a.y; r.y = 2.f*a.x*a.y; return r; }
__device__ __forceinline__ cf shflxor(cf v, int m){ cf r; r.x = __shfl_xor(v.x, m); r.y = __shfl_xor(v.y, m); return r; }
__device__ __forceinline__ int brev7(int l){ return (int)(__brev((unsigned)l) >> 25); }
__device__ __forceinline__ int padi(int i){ return i + (i >> 3); }
__device__ __forceinline__ cf h2cf(__half2 h){ float2 f = __half22float2(h); cf r; r.x = f.x; r.y = f.y; return r; }
__device__ __forceinline__ __half2 cf2h(cf v){ return __floats2half2_rn(v.x, v.y); }

__device__ __forceinline__ void radix3(cf a0, cf a1, cf a2, float s3, cf y[3]) {
  float tx = a1.x + a2.x, ty_ = a1.y + a2.y;
  float ux = a1.x - a2.x, uy = a1.y - a2.y;
  y[0].x = a0.x + tx;              y[0].y = a0.y + ty_;
  y[1].x = a0.x - 0.5f*tx - s3*uy; y[1].y = a0.y - 0.5f*ty_ + s3*ux;
  y[2].x = a0.x - 0.5f*tx + s3*uy; y[2].y = a0.y - 0.5f*ty_ - s3*ux;
}

// 384-point DFT across one 64-lane wave. SIGN=-1 fwd, +1 inverse (no 1/N scale).
// ONE sincos; all other twiddles derived by complex mul/squaring.
template<int SIGN>
__device__ __forceinline__ void fft384_wave(int l, const cf v[6], cf uA[3], cf uB[3]) {
  const float s3 = SIGN * 0.8660254037844386f;
  radix3(v[0], v[2], v[4], s3, uA);
  radix3(v[1], v[3], v[5], s3, uB);
  float sA, cA;
  __sincosf(SIGN * (2.0f * PI_F / 384.0f) * (float)l, &sA, &cA);
  cf wA1; wA1.x = cA; wA1.y = sA;
  cf wA2 = csqr(wA1);
  cf w6; w6.x = 0.5f; w6.y = s3;            // exp(SIGN*i*pi/3)
  cf wB1 = cmul(wA1, w6);
  cf wB2 = csqr(wB1);
  uA[1] = cmul(uA[1], wA1); uA[2] = cmul(uA[2], wA2);
  uB[1] = cmul(uB[1], wB1); uB[2] = cmul(uB[2], wB2);
  cf u = cmul(wA2, wA1);                    // exp(SIGN*i*pi*l/64)
  #pragma unroll
  for (int k1 = 0; k1 < 3; ++k1) {
    cf a = uA[k1], b = uB[k1];
    uA[k1] = cadd(a, b);
    uB[k1] = cmul(csub(a, b), u);
  }
  #pragma unroll
  for (int h = 32; h >= 1; h >>= 1) {
    u = csqr(u);                             // exp(SIGN*i*pi*l/h)
    const bool up = (l & h) != 0;
    #pragma unroll
    for (int k1 = 0; k1 < 3; ++k1) {
      cf pa = shflxor(uA[k1], h);
      cf pb = shflxor(uB[k1], h);
      cf na = up ? cmul(csub(uA[k1], pa), u) : cadd(uA[k1], pa);
      cf nb = up ? cmul(csub(uB[k1], pb), u) : cadd(uB[k1], pb);
      uA[k1] = na; uB[k1] = nb;
    }
  }
}

// ---------------- conv kernels ----------------
// Activations in ZERO-BORDER-PADDED NHWC bf16: act[b][py][px][c], logical (y,x)
// at padded (y+1,x+1). Border zeroed once per call.

__global__ void repack_mid_k(const float* __restrict__ ws_mid, __hip_bfloat16* __restrict__ wrep) {
  const int idx = blockIdx.x * 256 + threadIdx.x;
  if (idx >= 7*9*64*64) return;
  const int ci = idx & 63, co = (idx >> 6) & 63, tap = (idx >> 12) % 9, i = idx / (9*4096);
  wrep[idx] = __float2bfloat16(ws_mid[(((size_t)i*64 + co)*64 + ci)*9 + tap]);
}

__global__ void zero_border_k(__hip_bfloat16* __restrict__ a0, __hip_bfloat16* __restrict__ a1) {
  const int idx = blockIdx.x * 256 + threadIdx.x;
  if (idx >= 2*4*1540*8) return;
  const int s = idx & 7;
  int e = idx >> 3;
  const int buf = e / 6160; e -= buf*6160;
  const int b = e / 1540;  const int i = e - b*1540;
  int y, x;
  if (i < 386)       { y = 0;            x = i; }
  else if (i < 772)  { y = 385;          x = i - 386; }
  else if (i < 1156) { y = i - 772 + 1;  x = 0; }
  else               { y = i - 1156 + 1; x = 385; }
  __hip_bfloat16* p = (buf ? a1 : a0) + ((size_t)(b*PH + y)*PW + x)*64 + s*8;
  *(uint4*)p = make_uint4(0u, 0u, 0u, 0u);
}

__global__ void __launch_bounds__(256) conv_in_k(const float* __restrict__ xin,
                                                 const float* __restrict__ w,
                                                 const float* __restrict__ bias,
                                                 __hip_bfloat16* __restrict__ out) {
  __shared__ float tile[2][340];
  const int tx = threadIdx.x & 31, ty = threadIdx.x >> 5;
  const int x0 = blockIdx.x * 32, y0 = blockIdx.y * 8, b = blockIdx.z;
  for (int e = threadIdx.x; e < 680; e += 256) {
    int ci = e / 340, rr = e % 340;
    int iy = y0 - 1 + rr / 34, ix = x0 - 1 + rr % 34;
    float v = 0.f;
    if (iy >= 0 && iy < HH && ix >= 0 && ix < WW)
      v = xin[(b*2 + ci)*HW + iy*WW + ix];
    tile[ci][rr] = v;
  }
  __syncthreads();
  float acc[64];
  #pragma unroll
  for (int co = 0; co < 64; ++co) acc[co] = bias[co];
  #pragma unroll
  for (int ci = 0; ci < 2; ++ci) {
    float v0 = tile[ci][ty*34+tx],     v1 = tile[ci][ty*34+tx+1],     v2 = tile[ci][ty*34+tx+2];
    float v3 = tile[ci][(ty+1)*34+tx], v4 = tile[ci][(ty+1)*34+tx+1], v5 = tile[ci][(ty+1)*34+tx+2];
    float v6 = tile[ci][(ty+2)*34+tx], v7 = tile[ci][(ty+2)*34+tx+1], v8 = tile[ci][(ty+2)*34+tx+2];
    #pragma unroll
    for (int co = 0; co < 64; ++co) {
      const float* wp = w + co*18 + ci*9;
      float a = acc[co];
      a = fmaf(v0, wp[0], a); a = fmaf(v1, wp[1], a); a = fmaf(v2, wp[2], a);
      a = fmaf(v3, wp[3], a); a = fmaf(v4, wp[4], a); a = fmaf(v5, wp[5], a);
      a = fmaf(v6, wp[6], a); a = fmaf(v7, wp[7], a); a = fmaf(v8, wp[8], a);
      acc[co] = a;
    }
  }
  const size_t obase = ((size_t)(b*PH + y0 + ty + 1)*PW + (x0 + tx + 1))*64;
  #pragma unroll
  for (int s = 0; s < 8; ++s) {
    uint4 u;
    __hip_bfloat16* hp = (__hip_bfloat16*)&u;
    #pragma unroll
    for (int j = 0; j < 8; ++j) hp[j] = __float2bfloat16(acc[s*8 + j]);
    *(uint4*)(out + obase + s*8) = u;
  }
}

// MFMA implicit-GEMM mid conv: round-8 LDS-staged structure (measured 115us)
// reading the padded buffer (unconditional staging loads, no bounds-check VALU).
// Direct-global A-reads regressed (43.5KB tile > 32KB L1 — round 9, 162us).
__global__ void __launch_bounds__(256) conv_mid_mfma_k(
    const __hip_bfloat16* __restrict__ in,    // padded NHWC
    const __hip_bfloat16* __restrict__ wrep,  // [9][64][64] bf16
    const float* __restrict__ bias,
    __hip_bfloat16* __restrict__ out, int relu) {
  __shared__ __hip_bfloat16 atile[10*34*72];  // 48960 B
  const int tid = threadIdx.x;
  const int l = tid & 63, wv = tid >> 6;
  const int x0 = blockIdx.x * 32, y0 = blockIdx.y * 8, b = blockIdx.z;

  for (int e = tid; e < 340*8; e += 256) {
    int p = e >> 3, s = e & 7;
    uint4 v = *(const uint4*)(in + ((size_t)(b*PH + y0 + p/34)*PW + (x0 + p%34))*64 + s*8);
    *(uint4*)(&atile[p*72 + s*8]) = v;
  }

  floatx4 acc[4][4];
  #pragma unroll
  for (int mt = 0; mt < 4; ++mt)
    #pragma unroll
    for (int nt = 0; nt < 4; ++nt)
      acc[mt][nt] = (floatx4){0.f, 0.f, 0.f, 0.f};

  const int kseg = l >> 4;
  const int lr = l & 15;

  // prefetch tap 0 weights while atile staging is in flight
  const __hip_bfloat16* wlane = wrep + lr*64 + kseg*8;
  short8 bf[4][2];
  #pragma unroll
  for (int nt = 0; nt < 4; ++nt) {
    bf[nt][0] = *(const short8*)(wlane + nt*1024);
    bf[nt][1] = *(const short8*)(wlane + nt*1024 + 32);
  }

  __syncthreads();

  #pragma unroll 1
  for (int tap = 0; tap < 9; ++tap) {
    short8 bfn[4][2];
    if (tap < 8) {
      const __hip_bfloat16* wn = wlane + (tap + 1)*4096;
      #pragma unroll
      for (int nt = 0; nt < 4; ++nt) {
        bfn[nt][0] = *(const short8*)(wn + nt*1024);
        bfn[nt][1] = *(const short8*)(wn + nt*1024 + 32);
      }
    }
    const int dy = tap / 3, dx = tap - dy*3;
    short8 af[4][2];
    #pragma unroll
    for (int mt = 0; mt < 4; ++mt) {
      const int ry = 2*wv + (mt >> 1) + dy;
      const int px = (mt & 1)*16 + lr + dx;
      const __hip_bfloat16* ap = &atile[(ry*34 + px)*72 + kseg*8];
      af[mt][0] = *(const short8*)(ap);
      af[mt][1] = *(const short8*)(ap + 32);
    }
    #pragma unroll
    for (int mt = 0; mt < 4; ++mt)
      #pragma unroll
      for (int nt = 0; nt < 4; ++nt) {
        acc[mt][nt] = __builtin_amdgcn_mfma_f32_16x16x32_bf16(af[mt][0], bf[nt][0], acc[mt][nt], 0, 0, 0);
        acc[mt][nt] = __builtin_amdgcn_mfma_f32_16x16x32_bf16(af[mt][1], bf[nt][1], acc[mt][nt], 0, 0, 0);
      }
    if (tap < 8) {
      #pragma unroll
      for (int nt = 0; nt < 4; ++nt) { bf[nt][0] = bfn[nt][0]; bf[nt][1] = bfn[nt][1]; }
    }
  }

  // LDS-transpose epilogue -> coalesced 16B stores
  __syncthreads();
  __hip_bfloat16* otile = atile;        // [256 pixels][72 pad]
  #pragma unroll
  for (int mt = 0; mt < 4; ++mt) {
    const int row = 2*wv + (mt >> 1);
    #pragma unroll
    for (int nt = 0; nt < 4; ++nt) {
      const int ch = nt*16 + lr;
      const float bv = bias[ch];
      #pragma unroll
      for (int rr = 0; rr < 4; ++rr) {
        const int px = (mt & 1)*16 + kseg*4 + rr;
        float v = acc[mt][nt][rr] + bv;
        if (relu) v = fmaxf(v, 0.f);
        otile[(row*32 + px)*72 + ch] = __float2bfloat16(v);
      }
    }
  }
  __syncthreads();
  #pragma unroll
  for (int iter = 0; iter < 8; ++iter) {
    const int p = iter*32 + (tid >> 3), s = tid & 7;
    const int row = p >> 5, px = p & 31;
    uint4 v = *(const uint4*)(&otile[p*72 + s*8]);
    *(uint4*)(out + ((size_t)(b*PH + y0 + row + 1)*PW + (x0 + px + 1))*64 + s*8) = v;
  }
}

// conv_out (co=2) + CG init, LDS-staged from padded buffer
__global__ void __launch_bounds__(256) conv_out_k(const __hip_bfloat16* __restrict__ in,
                                                  const float* __restrict__ w,
                                                  const float* __restrict__ bias,
                                                  const float* __restrict__ xcur,
                                                  const float* __restrict__ under,
                                                  const float* __restrict__ lam,
                                                  cf* __restrict__ r, cf* __restrict__ p,
                                                  cf* __restrict__ xc, float* __restrict__ scL) {
  __shared__ __hip_bfloat16 atile[340*72];
  __shared__ float wl[2*64*9];
  __shared__ float wsum[4];
  const int tid = threadIdx.x;
  const int tx = tid & 31, ty = tid >> 5;
  const int x0 = blockIdx.x * 32, y0 = blockIdx.y * 8, b = blockIdx.z;

  for (int e = tid; e < 340*8; e += 256) {
    int pp = e >> 3, s = e & 7;
    uint4 v = *(const uint4*)(in + ((size_t)(b*PH + y0 + pp/34)*PW + (x0 + pp%34))*64 + s*8);
    *(uint4*)(&atile[pp*72 + s*8]) = v;
  }
  for (int e = tid; e < 2*64*9; e += 256) wl[e] = w[e];
  __syncthreads();

  float a0 = bias[0], a1 = bias[1];
  #pragma unroll 1
  for (int tap = 0; tap < 9; ++tap) {
    const int dy = tap / 3, dx = tap - dy*3;
    const __hip_bfloat16* ap = &atile[((ty + dy)*34 + tx + dx)*72];
    #pragma unroll
    for (int s = 0; s < 8; ++s) {
      short8 v8 = *(const short8*)(ap + s*8);
      const __hip_bfloat16* hv = (const __hip_bfloat16*)&v8;
      #pragma unroll
      for (int j = 0; j < 8; ++j) {
        const float f = __bfloat162float(hv[j]);
        a0 = fmaf(f, wl[(s*8 + j)*9 + tap], a0);
        a1 = fmaf(f, wl[(64 + s*8 + j)*9 + tap], a1);
      }
    }
  }
  const float lamv = lam[0];
  const int y = y0 + ty, x = x0 + tx;
  const int idx2 = y*WW + x;
  float xv0 = xcur[b*2*HW + idx2],  xv1 = xcur[b*2*HW + HW + idx2];
  float u0  = under[b*2*HW + idx2], u1  = under[b*2*HW + HW + idx2];
  float r0 = u0 + lamv * (xv0 + a0);
  float r1 = u1 + lamv * (xv1 + a1);
  const int cidx = b*HW + idx2;
  cf vv; vv.x = r0; vv.y = r1;
  r[cidx] = vv; p[cidx] = vv;
  cf zz; zz.x = 0.f; zz.y = 0.f; xc[cidx] = zz;
  float partial = r0*r0 + r1*r1;
  for (int off = 32; off; off >>= 1) partial += __shfl_down(partial, off);
  const int l = tid & 63, wvid = tid >> 6;
  if (l == 0) wsum[wvid] = partial;
  __syncthreads();
  if (tid == 0) atomicAdd(&scL[b], wsum[0]+wsum[1]+wsum[2]+wsum[3]);
}

// ---------------- CG / FFT kernels ----------------
// scL (128 floats/layer): rtr[it*4+b] (it 0..10), pAp[48+it*4+b].
// pAp assembled via Parseval: pass_a adds lam*||p||^2, pass_b adds (1/N)*sum|Km|^2.
// pass_c: Ap in registers -> x,r updates + EXACT rtr_{it+1} reduce. No Ap buffer.

// pass_a: p_new = r + beta*p_old (it>0), row FFT(csm*p) -> t (fp16); c==0 block
// writes p_new and reduces lam*||p||^2 into the pAp slot.
__global__ void __launch_bounds__(256) pass_a_k(const cf* __restrict__ rres,
                                                const cf* __restrict__ pold, cf* __restrict__ pnew,
                                                const cf* __restrict__ csm, __half2* __restrict__ t,
                                                const float* __restrict__ lam,
                                                float* __restrict__ scL, int it) {
  __shared__ cf rowbuf[4][434];
  __shared__ float wsum[4];
  const int l = threadIdx.x & 63, wv = threadIdx.x >> 6;
  const int y = blockIdx.x * 4 + wv;
  const int c = blockIdx.y, b = blockIdx.z;
  const int rowoff = b*HW + y*WW;
  cf pv[6];
  float pnorm = 0.f;
  if (it == 0) {
    #pragma unroll
    for (int m = 0; m < 6; ++m) {
      pv[m] = pold[rowoff + l + 64*m];
      pnorm += pv[m].x*pv[m].x + pv[m].y*pv[m].y;
    }
  } else {
    const float beta = scL[it*4 + b] / scL[(it-1)*4 + b];
    #pragma unroll
    for (int m = 0; m < 6; ++m) {
      const int idx = rowoff + l + 64*m;
      cf rv = rres[idx], po = pold[idx];
      pv[m].x = rv.x + beta*po.x; pv[m].y = rv.y + beta*po.y;
      pnorm += pv[m].x*pv[m].x + pv[m].y*pv[m].y;
      if (c == 0) pnew[idx] = pv[m];
    }
  }
  const cf* crow = csm + (b*CC + c)*HW + y*WW;
  cf v[6];
  #pragma unroll
  for (int m = 0; m < 6; ++m) v[m] = cmul(crow[l + 64*m], pv[m]);
  cf uA[3], uB[3];
  fft384_wave<-1>(l, v, uA, uB);
  const int R3 = 3 * brev7(l);
  cf* rb = rowbuf[wv];                  // wave-private
  #pragma unroll
  for (int k1 = 0; k1 < 3; ++k1) { rb[padi(k1 + R3)] = uA[k1]; rb[padi(k1 + R3 + 3)] = uB[k1]; }
  __half2* trow = t + (b*CC + c)*HW + y*WW;
  #pragma unroll
  for (int m = 0; m < 6; ++m) trow[l + 64*m] = cf2h(rb[padi(l + 64*m)]);
  if (c == 0) {                         // block-uniform branch
    #pragma unroll
    for (int off = 32; off; off >>= 1) pnorm += __shfl_down(pnorm, off);
    if (l == 0) wsum[wv] = pnorm;
    __syncthreads();
    if (threadIdx.x == 0)
      atomicAdd(&scL[48 + it*4 + b], lam[0] * (wsum[0]+wsum[1]+wsum[2]+wsum[3]));
  }
}

// pass_b: col FFT, mask (+ reduce (1/N)*sum|Km|^2 into pAp), col IFFT
__global__ void __launch_bounds__(256) pass_b_k(__half2* __restrict__ t, const float* __restrict__ mask,
                                                float* __restrict__ scL, int it) {
  __shared__ cf tile[431*9];
  __shared__ float wsumB[4];
  const int b = blockIdx.z, c = blockIdx.y, x0 = blockIdx.x * 8;
  __half2* base = t + (b*CC + c)*HW;
  for (int e = threadIdx.x; e < 3072; e += 256) {
    int y = e >> 3, xx = e & 7;
    tile[padi(y)*9 + xx] = h2cf(base[y*WW + x0 + xx]);
  }
  __syncthreads();
  const int l = threadIdx.x & 63, wv = threadIdx.x >> 6;
  const int R3 = 3 * brev7(l);
  float kss = 0.f;
  for (int rep = 0; rep < 2; ++rep) {
    const int xx = wv*2 + rep, x = x0 + xx;
    cf v[6];
    #pragma unroll
    for (int m = 0; m < 6; ++m) v[m] = tile[padi(l + 64*m)*9 + xx];
    cf uA[3], uB[3];
    fft384_wave<-1>(l, v, uA, uB);
    const float* mrow = mask + b*HW + x;
    #pragma unroll
    for (int k1 = 0; k1 < 3; ++k1) {
      float mA = mrow[(k1 + R3)*WW], mB = mrow[(k1 + R3 + 3)*WW];
      uA[k1].x *= mA; uA[k1].y *= mA; uB[k1].x *= mB; uB[k1].y *= mB;
      kss += uA[k1].x*uA[k1].x + uA[k1].y*uA[k1].y + uB[k1].x*uB[k1].x + uB[k1].y*uB[k1].y;
    }
    __syncthreads();
    #pragma unroll
    for (int k1 = 0; k1 < 3; ++k1) { tile[padi(k1 + R3)*9 + xx] = uA[k1]; tile[padi(k1 + R3 + 3)*9 + xx] = uB[k1]; }
    __syncthreads();
    #pragma unroll
    for (int m = 0; m < 6; ++m) v[m] = tile[padi(l + 64*m)*9 + xx];
    fft384_wave<1>(l, v, uA, uB);
    const float s = 1.0f / 384.0f;
    #pragma unroll
    for (int k1 = 0; k1 < 3; ++k1) {
      uA[k1].x *= s; uA[k1].y *= s; uB[k1].x *= s; uB[k1].y *= s;
      tile[padi(k1 + R3)*9 + xx] = uA[k1]; tile[padi(k1 + R3 + 3)*9 + xx] = uB[k1];
    }
    __syncthreads();
  }
  for (int e = threadIdx.x; e < 3072; e += 256) {
    int y = e >> 3, xx = e & 7;
    base[y*WW + x0 + xx] = cf2h(tile[padi(y)*9 + xx]);
  }
  #pragma unroll
  for (int off = 32; off; off >>= 1) kss += __shfl_down(kss, off);
  if (l == 0) wsumB[wv] = kss;
  __syncthreads();
  if (threadIdx.x == 0)
    atomicAdd(&scL[48 + it*4 + b], (wsumB[0]+wsumB[1]+wsumB[2]+wsumB[3]) * (1.0f/147456.0f));
}

// pass_c: row IFFT + coil reduce -> Ap in registers; x += alpha*p, r -= alpha*Ap,
// reduce exact rtr_{it+1}. Last iter writes planar output instead of xc.
__global__ void __launch_bounds__(256) pass_c_k(const __half2* __restrict__ t, const cf* __restrict__ csm,
                                                const cf* __restrict__ p, cf* __restrict__ rres,
                                                cf* __restrict__ xc, const float* __restrict__ lam,
                                                float* __restrict__ scL, int it,
                                                float* __restrict__ xout) {
  __shared__ cf rowbuf[4][434];
  __shared__ cf redbuf[3][384];
  const int l = threadIdx.x & 63, wv = threadIdx.x >> 6;
  const int y = blockIdx.x, b = blockIdx.y;
  const int R3 = 3 * brev7(l);
  cf* rb = rowbuf[wv];                  // wave-private
  cf acc[6] = {};
  #pragma unroll 1
  for (int ci = 0; ci < 2; ++ci) {
    const int c = wv*2 + ci;
    const __half2* trow = t + (b*CC + c)*HW + y*WW;
    cf v[6];
    #pragma unroll
    for (int m = 0; m < 6; ++m) v[m] = h2cf(trow[l + 64*m]);
    cf uA[3], uB[3];
    fft384_wave<1>(l, v, uA, uB);
    #pragma unroll
    for (int k1 = 0; k1 < 3; ++k1) { rb[padi(k1 + R3)] = uA[k1]; rb[padi(k1 + R3 + 3)] = uB[k1]; }
    const cf* crow = csm + (b*CC + c)*HW + y*WW;
    #pragma unroll
    for (int m = 0; m < 6; ++m) {
      cf cs = crow[l + 64*m];
      cf wz = rb[padi(l + 64*m)];
      acc[m].x += cs.x*wz.x + cs.y*wz.y;
      acc[m].y += cs.x*wz.y - cs.y*wz.x;
    }
  }
  if (wv > 0) {
    #pragma unroll
    for (int m = 0; m < 6; ++m) redbuf[wv - 1][l + 64*m] = acc[m];
  }
  __syncthreads();
  if (wv == 0) {
    #pragma unroll
    for (int m = 0; m < 6; ++m) {
      #pragma unroll
      for (int j = 0; j < 3; ++j) {
        cf o = redbuf[j][l + 64*m];
        acc[m].x += o.x; acc[m].y += o.y;
      }
    }
    const float lamv = lam[0];
    const float sc384 = 1.0f / 384.0f;
    const float alpha = scL[it*4 + b] / scL[48 + it*4 + b];
    const int rowoff = b*HW + y*WW;
    float partial = 0.f;
    #pragma unroll
    for (int m = 0; m < 6; ++m) {
      const int idx = rowoff + l + 64*m;
      cf pv = p[idx];
      cf ap; ap.x = acc[m].x*sc384 + lamv*pv.x; ap.y = acc[m].y*sc384 + lamv*pv.y;
      cf xv = xc[idx]; xv.x += alpha*pv.x; xv.y += alpha*pv.y;
      cf rv = rres[idx]; rv.x -= alpha*ap.x; rv.y -= alpha*ap.y;
      rres[idx] = rv;
      partial += rv.x*rv.x + rv.y*rv.y;
      if (it == CGITERS - 1) {
        const int rem = y*WW + l + 64*m;
        xout[b*2*HW + rem] = xv.x;
        xout[b*2*HW + HW + rem] = xv.y;
      } else {
        xc[idx] = xv;
      }
    }
    #pragma unroll
    for (int off = 32; off; off >>= 1) partial += __shfl_down(partial, off);
    if (l == 0) atomicAdd(&scL[(it+1)*4 + b], partial);
  }
}

__global__ void zero_sc_k(float* sc) {
  for (int i = threadIdx.x; i < NLAYERS*128; i += 256) sc[i] = 0.f;
}

extern "C" void kernel_launch(void* const* d_in, const int* in_sizes, int n_in,
                              void* d_out, int out_size, void* d_ws, size_t ws_size,
                              hipStream_t stream) {
  (void)in_sizes; (void)n_in; (void)out_size; (void)ws_size;
  const float* under  = (const float*)d_in[0];
  const cf*    csm    = (const cf*)d_in[1];
  const float* mask   = (const float*)d_in[2];
  const float* lam    = (const float*)d_in[3];
  const float* w_in   = (const float*)d_in[4];
  const float* b_in   = (const float*)d_in[5];
  const float* ws_mid = (const float*)d_in[6];
  const float* bs_mid = (const float*)d_in[7];
  const float* w_out  = (const float*)d_in[8];
  const float* b_out  = (const float*)d_in[9];
  float* xcur = (float*)d_out;

  char* bws = (char*)d_ws;
  size_t off = 0;
  auto carve = [&](size_t bytes) { char* pp = bws + off; off += (bytes + 255) & ~(size_t)255; return (void*)pp; };
  __hip_bfloat16* actA = (__hip_bfloat16*)carve((size_t)BB*PH*PW*64*2);
  __hip_bfloat16* actB = (__hip_bfloat16*)carve((size_t)BB*PH*PW*64*2);
  __half2* t = (__half2*)carve((size_t)BB*CC*HW*4);
  cf* rbuf0 = (cf*)carve((size_t)BB*HW*8);
  cf* pbuf0 = (cf*)carve((size_t)BB*HW*8);
  cf* pbuf1 = (cf*)carve((size_t)BB*HW*8);
  cf* xc    = (cf*)carve((size_t)BB*HW*8);
  float* sc = (float*)carve(4096);
  __hip_bfloat16* wrep = (__hip_bfloat16*)carve((size_t)7*9*64*64*2);

  hipMemcpyAsync(xcur, under, (size_t)BB*2*HW*sizeof(float), hipMemcpyDeviceToDevice, stream);

  zero_sc_k<<<1, 256, 0, stream>>>(sc);
  zero_border_k<<<(2*4*1540*8 + 255)/256, 256, 0, stream>>>(actA, actB);
  repack_mid_k<<<(7*9*64*64 + 255)/256, 256, 0, stream>>>(ws_mid, wrep);

  dim3 cgrid(WW/32, HH/8, BB);       // conv kernels (32x8 tiles)
  dim3 agrid(HH/4, CC, BB);
  dim3 bgrid(WW/8, CC, BB);
  dim3 c2grid(HH, BB);               // pass_c: one row per block

  __hip_bfloat16* bufs[2] = { actA, actB };
  cf* pb[2] = { pbuf0, pbuf1 };

  for (int layer = 0; layer < NLAYERS; ++layer) {
    float* scL = sc + layer*128;
    conv_in_k<<<cgrid, 256, 0, stream>>>(xcur, w_in, b_in, bufs[0]);
    for (int i = 0; i < 7; ++i) {
      conv_mid_mfma_k<<<cgrid, 256, 0, stream>>>(bufs[i & 1], wrep + (size_t)i*9*4096,
                                                 bs_mid + i*64, bufs[(i + 1) & 1], (i % 2 == 0) ? 1 : 0);
    }
    conv_out_k<<<cgrid, 256, 0, stream>>>(bufs[1], w_out, b_out, xcur, under, lam,
                                          rbuf0, pbuf0, xc, scL);
    for (int it = 0; it < CGITERS; ++it) {
      cf* pold = (it == 0) ? pbuf0 : pb[(it + 1) & 1];
      cf* pnew = (it == 0) ? pbuf0 : pb[it & 1];
      pass_a_k<<<agrid, 256, 0, stream>>>(rbuf0, pold, pnew, csm, t, lam, scL, it);
      pass_b_k<<<bgrid, 256, 0, stream>>>(t, mask, scL, it);
      pass_c_k<<<c2grid, 256, 0, stream>>>(t, csm, pnew, rbuf0, xc, lam, scL, it, xcur);
    }
  }
}